// Round 3
// baseline (371.144 us; speedup 1.0000x reference)
//
#include <hip/hip_runtime.h>
#include <stdint.h>

typedef unsigned short u16;
typedef __bf16 bf16x8 __attribute__((ext_vector_type(8)));
typedef float f32x4v __attribute__((ext_vector_type(4)));

#define BB 8
#define SS 2048
#define TT 2048
#define DD 1024
#define LN_EPS 1e-5f

__device__ __forceinline__ float sigm(float x){ return 1.f/(1.f+__expf(-x)); }

__device__ __forceinline__ u16 f2bf(float v){
  uint32_t x = __builtin_bit_cast(uint32_t, v);
  uint32_t r = x + 0x7fffu + ((x >> 16) & 1u);
  return (u16)(r >> 16);
}
__device__ __forceinline__ float bf2f(u16 u){
  return __builtin_bit_cast(float, (uint32_t)u << 16);
}

__device__ __forceinline__ void gload16(const void* g, void* l){
  __builtin_amdgcn_global_load_lds((const __attribute__((address_space(1))) unsigned int*)g,
                                   (__attribute__((address_space(3))) unsigned int*)l, 16, 0, 0);
}

// bijective XCD swizzle (m204 variant): contiguous chunk per XCD
__device__ __forceinline__ int xcd_swizzle(int orig, int nwg){
  int q = nwg >> 3, r = nwg & 7;
  int xcd = orig & 7, idx = orig >> 3;
  return (xcd < r ? xcd*(q+1) : r*(q+1) + (xcd-r)*q) + idx;
}

// ---------------- tiny prep kernels ----------------
__global__ void prep_small(const float* qs, const float* ks, const float* vs,
                           float* sq, float* sk, float* svs){
  int i = blockIdx.x*blockDim.x + threadIdx.x;
  if (i < DD){ sq[i] = sigm(qs[i]); sk[i] = sigm(ks[i]); svs[i] = sigm(vs[i]); }
}

__global__ __launch_bounds__(256) void prep_sv(const float* __restrict__ Wov, const float* __restrict__ bov,
                        const float* __restrict__ svs, float* __restrict__ sv){
  int d = blockIdx.x, tid = threadIdx.x;
  float a = 0.f, b = 0.f;
  for (int j = tid; j < DD; j += 256){
    float s = svs[j];
    a += Wov[(size_t)d*DD + j]*s;
    b += Wov[(size_t)(d+DD)*DD + j]*s;
  }
  #pragma unroll
  for (int o = 32; o; o >>= 1){ a += __shfl_xor(a,o); b += __shfl_xor(b,o); }
  __shared__ float sa[4], sb[4];
  int lane = tid & 63, w = tid >> 6;
  if (!lane){ sa[w] = a; sb[w] = b; }
  __syncthreads();
  if (tid == 0){
    float A = sa[0]+sa[1]+sa[2]+sa[3] + bov[d];
    float Bv= sb[0]+sb[1]+sb[2]+sb[3] + bov[DD+d];
    sv[d] = sigm(A) * tanhf(Bv);
  }
}

__global__ void f32_to_bf16_k(const float* __restrict__ src, u16* __restrict__ dst, int n){
  for (int i = (blockIdx.x*blockDim.x + threadIdx.x)*4; i < n; i += gridDim.x*blockDim.x*4){
    float4 v = *(const float4*)(src + i);
    ushort4 o; o.x = f2bf(v.x); o.y = f2bf(v.y); o.z = f2bf(v.z); o.w = f2bf(v.w);
    *(ushort4*)(dst + i) = o;
  }
}

__global__ void scale_k_k(const float* __restrict__ Y, const float* __restrict__ sk,
                          u16* __restrict__ kbf, int n){
  for (int i = (blockIdx.x*blockDim.x + threadIdx.x)*4; i < n; i += gridDim.x*blockDim.x*4){
    float4 v = *(const float4*)(Y + i);
    float4 s = *(const float4*)(sk + (i & (DD-1)));
    ushort4 o; o.x = f2bf(v.x*s.x); o.y = f2bf(v.y*s.y); o.z = f2bf(v.z*s.z); o.w = f2bf(v.w*s.w);
    *(ushort4*)(kbf + i) = o;
  }
}

__global__ __launch_bounds__(256) void scale_transpose_v(const float* __restrict__ Y,
                            const float* __restrict__ sv, u16* __restrict__ vT){
  __shared__ float tile[64][65];
  int tx = threadIdx.x & 15, ty = threadIdx.x >> 4;
  int b = blockIdx.z;
  int t0 = blockIdx.x*64, d0 = blockIdx.y*64;
  const float* Yb = Y + ((size_t)b*TT + t0)*DD + d0;
  float4 s = *(const float4*)(sv + d0 + tx*4);
  #pragma unroll
  for (int it = 0; it < 4; ++it){
    int t = ty + it*16;
    float4 y = *(const float4*)(Yb + (size_t)t*DD + tx*4);
    tile[t][tx*4+0] = y.x*s.x; tile[t][tx*4+1] = y.y*s.y;
    tile[t][tx*4+2] = y.z*s.z; tile[t][tx*4+3] = y.w*s.w;
  }
  __syncthreads();
  u16* ob = vT + ((size_t)b*DD + d0)*TT + t0;
  #pragma unroll
  for (int it = 0; it < 4; ++it){
    int dd = ty + it*16;
    ushort4 o;
    o.x = f2bf(tile[tx*4+0][dd]); o.y = f2bf(tile[tx*4+1][dd]);
    o.z = f2bf(tile[tx*4+2][dd]); o.w = f2bf(tile[tx*4+3][dd]);
    *(ushort4*)(ob + (size_t)dd*TT + tx*4) = o;
  }
}

// ---------------- GEMM: C[m][n] = sum_k A[m][k]*B[n][k] (both bf16, B^T layout) ----------------
// OUTMODE: 0 = f32, 1 = bf16, 2 = bf16 with bias
template<int OUTMODE>
__global__ __launch_bounds__(256, 2)
void gemm_bt(const u16* __restrict__ A, const u16* __restrict__ B,
             void* __restrict__ Cv, const float* __restrict__ bias,
             int K, int lda, int ldb, int ldc,
             size_t sA, size_t sB, size_t sC, int ntx, int nty)
{
  __shared__ u16 As[128*32];
  __shared__ u16 Bs[128*32];
  const int tid = threadIdx.x;
  const int lane = tid & 63;
  const int w = tid >> 6;
  const int wm = w >> 1, wn = w & 1;
  const int nwg = ntx * nty;
  const int sw = xcd_swizzle(blockIdx.x + blockIdx.y * ntx, nwg);
  const int bx = sw % ntx, by = sw / ntx;
  const size_t bz = blockIdx.z;
  const int tM = by * 128;
  const int tN = bx * 128;
  const u16* Ab = A + bz*sA;
  const u16* Bb = B + bz*sB;

  f32x4v acc[4][4];
  #pragma unroll
  for (int m = 0; m < 4; ++m)
    #pragma unroll
    for (int n = 0; n < 4; ++n) acc[m][n] = (f32x4v){0.f,0.f,0.f,0.f};

  const int srow = lane >> 2;
  const int scol = (lane & 3) * 8;
  const int frow = lane & 15;
  const int fcol = (lane >> 4) * 8;

  for (int k0 = 0; k0 < K; k0 += 32){
    #pragma unroll
    for (int c = 0; c < 2; ++c){
      const int chunk = w*2 + c;
      gload16(Ab + (size_t)(tM + chunk*16 + srow)*lda + (k0 + scol), &As[chunk*512]);
      gload16(Bb + (size_t)(tN + chunk*16 + srow)*ldb + (k0 + scol), &Bs[chunk*512]);
    }
    __syncthreads();
    bf16x8 af[4], bfv[4];
    #pragma unroll
    for (int m = 0; m < 4; ++m) af[m]  = *(const bf16x8*)&As[(wm*64 + m*16 + frow)*32 + fcol];
    #pragma unroll
    for (int n = 0; n < 4; ++n) bfv[n] = *(const bf16x8*)&Bs[(wn*64 + n*16 + frow)*32 + fcol];
    #pragma unroll
    for (int m = 0; m < 4; ++m)
      #pragma unroll
      for (int n = 0; n < 4; ++n)
        acc[m][n] = __builtin_amdgcn_mfma_f32_16x16x32_bf16(af[m], bfv[n], acc[m][n], 0, 0, 0);
    __syncthreads();
  }

  const int erow = (lane >> 4) * 4;
  const int ecol = lane & 15;
  #pragma unroll
  for (int m = 0; m < 4; ++m){
    #pragma unroll
    for (int n = 0; n < 4; ++n){
      const int row0 = tM + wm*64 + m*16 + erow;
      const int col  = tN + wn*64 + n*16 + ecol;
      if (OUTMODE == 0){
        float* C = (float*)Cv + bz*sC;
        #pragma unroll
        for (int r = 0; r < 4; ++r) C[(size_t)(row0+r)*ldc + col] = acc[m][n][r];
      } else {
        float bv = (OUTMODE == 2) ? bias[col] : 0.f;
        u16* C = (u16*)Cv + bz*sC;
        #pragma unroll
        for (int r = 0; r < 4; ++r) C[(size_t)(row0+r)*ldc + col] = f2bf(acc[m][n][r] + bv);
      }
    }
  }
}

// ---------------- LN on q rows (in-place, bf16), folds g1,b1, sigmoid(qs), 1/sqrt(D) ----------------
__global__ __launch_bounds__(256) void ln_q(u16* __restrict__ qb, const float* __restrict__ g1,
                     const float* __restrict__ b1, const float* __restrict__ sq){
  int r = blockIdx.x, tid = threadIdx.x;
  u16* row = qb + (size_t)r*DD;
  ushort4 u = *(ushort4*)(row + tid*4);
  float x0 = bf2f(u.x), x1 = bf2f(u.y), x2 = bf2f(u.z), x3 = bf2f(u.w);
  float s = x0+x1+x2+x3;
  float ss = x0*x0 + x1*x1 + x2*x2 + x3*x3;
  #pragma unroll
  for (int o = 32; o; o >>= 1){ s += __shfl_xor(s,o); ss += __shfl_xor(ss,o); }
  __shared__ float sa[4], sb[4];
  int lane = tid & 63, w = tid >> 6;
  if (!lane){ sa[w] = s; sb[w] = ss; }
  __syncthreads();
  s  = sa[0]+sa[1]+sa[2]+sa[3];
  ss = sb[0]+sb[1]+sb[2]+sb[3];
  float mean = s * (1.f/DD);
  float var  = ss * (1.f/DD) - mean*mean;
  float rs = rsqrtf(var + LN_EPS);
  float4 g = *(const float4*)(g1 + tid*4);
  float4 b = *(const float4*)(b1 + tid*4);
  float4 q = *(const float4*)(sq + tid*4);
  ushort4 o;
  o.x = f2bf(((x0-mean)*rs*g.x + b.x) * q.x * 0.03125f);
  o.y = f2bf(((x1-mean)*rs*g.y + b.y) * q.y * 0.03125f);
  o.z = f2bf(((x2-mean)*rs*g.z + b.z) * q.z * 0.03125f);
  o.w = f2bf(((x3-mean)*rs*g.w + b.w) * q.w * 0.03125f);
  *(ushort4*)(row + tid*4) = o;
}

// ---------------- softmax rows of S (bf16 in), write bf16 P in place ----------------
__global__ __launch_bounds__(256) void softmax_rows(u16* __restrict__ Sb, const int* __restrict__ mask){
  int r = blockIdx.x, tid = threadIdx.x;
  u16* row = Sb + ((size_t)blockIdx.y*SS + r)*TT;
  const int* mrow = mask + (size_t)r*TT;
  ushort4 u0 = *(const ushort4*)(row + tid*8);
  ushort4 u1 = *(const ushort4*)(row + tid*8 + 4);
  int4 m0 = *(const int4*)(mrow + tid*8);
  int4 m1 = *(const int4*)(mrow + tid*8 + 4);
  float x[8] = {bf2f(u0.x),bf2f(u0.y),bf2f(u0.z),bf2f(u0.w),
                bf2f(u1.x),bf2f(u1.y),bf2f(u1.z),bf2f(u1.w)};
  int mm[8] = {m0.x,m0.y,m0.z,m0.w,m1.x,m1.y,m1.z,m1.w};
  #pragma unroll
  for (int j = 0; j < 8; ++j) if (mm[j] == 0) x[j] = -INFINITY;
  float mx = x[0];
  #pragma unroll
  for (int j = 1; j < 8; ++j) mx = fmaxf(mx, x[j]);
  #pragma unroll
  for (int o = 32; o; o >>= 1) mx = fmaxf(mx, __shfl_xor(mx,o));
  __shared__ float sm[4], ssum[4];
  int lane = tid & 63, w = tid >> 6;
  if (!lane) sm[w] = mx;
  __syncthreads();
  mx = fmaxf(fmaxf(sm[0],sm[1]), fmaxf(sm[2],sm[3]));
  float e[8]; float sum = 0.f;
  #pragma unroll
  for (int j = 0; j < 8; ++j){ e[j] = __expf(x[j]-mx); sum += e[j]; }
  #pragma unroll
  for (int o = 32; o; o >>= 1) sum += __shfl_xor(sum,o);
  if (!lane) ssum[w] = sum;
  __syncthreads();
  sum = ssum[0]+ssum[1]+ssum[2]+ssum[3];
  float inv = 1.f/sum;
  ushort4 o0, o1;
  o0.x = f2bf(e[0]*inv); o0.y = f2bf(e[1]*inv); o0.z = f2bf(e[2]*inv); o0.w = f2bf(e[3]*inv);
  o1.x = f2bf(e[4]*inv); o1.y = f2bf(e[5]*inv); o1.z = f2bf(e[6]*inv); o1.w = f2bf(e[7]*inv);
  *(ushort4*)(row + tid*8) = o0;
  *(ushort4*)(row + tid*8 + 4) = o1;
}

// ---------------- final LN over X + out, in-place in d_out (f32) ----------------
__global__ __launch_bounds__(256) void final_ln(const float* __restrict__ X, float* __restrict__ out,
                         const float* __restrict__ g2, const float* __restrict__ b2){
  int r = blockIdx.x, tid = threadIdx.x;
  const float* xr = X + (size_t)r*DD;
  float* orw = out + (size_t)r*DD;
  float4 xv = *(const float4*)(xr + tid*4);
  float4 ov = *(const float4*)(orw + tid*4);
  float z0 = xv.x+ov.x, z1 = xv.y+ov.y, z2 = xv.z+ov.z, z3 = xv.w+ov.w;
  float s = z0+z1+z2+z3;
  float ss = z0*z0 + z1*z1 + z2*z2 + z3*z3;
  #pragma unroll
  for (int o = 32; o; o >>= 1){ s += __shfl_xor(s,o); ss += __shfl_xor(ss,o); }
  __shared__ float sa[4], sb[4];
  int lane = tid & 63, w = tid >> 6;
  if (!lane){ sa[w] = s; sb[w] = ss; }
  __syncthreads();
  s  = sa[0]+sa[1]+sa[2]+sa[3];
  ss = sb[0]+sb[1]+sb[2]+sb[3];
  float mean = s * (1.f/DD);
  float var  = ss * (1.f/DD) - mean*mean;
  float rs = rsqrtf(var + LN_EPS);
  float4 g = *(const float4*)(g2 + tid*4);
  float4 b = *(const float4*)(b2 + tid*4);
  float4 o;
  o.x = (z0-mean)*rs*g.x + b.x;
  o.y = (z1-mean)*rs*g.y + b.y;
  o.z = (z2-mean)*rs*g.z + b.z;
  o.w = (z3-mean)*rs*g.w + b.w;
  *(float4*)(orw + tid*4) = o;
}

extern "C" void kernel_launch(void* const* d_in, const int* in_sizes, int n_in,
                              void* d_out, int out_size, void* d_ws, size_t ws_size,
                              hipStream_t stream)
{
  const float* X  = (const float*)d_in[0];
  const float* Y  = (const float*)d_in[1];
  const float* qs = (const float*)d_in[2];
  const float* ks = (const float*)d_in[3];
  const float* vs = (const float*)d_in[4];
  const float* Wq = (const float*)d_in[5];
  const float* bq = (const float*)d_in[6];
  const float* g1 = (const float*)d_in[7];
  const float* b1 = (const float*)d_in[8];
  const float* Wov= (const float*)d_in[9];
  const float* bov= (const float*)d_in[10];
  const float* g2 = (const float*)d_in[11];
  const float* b2 = (const float*)d_in[12];
  const int* mask = (const int*)d_in[13];
  float* out = (float*)d_out;
  (void)in_sizes; (void)n_in; (void)out_size;

  char* ws = (char*)d_ws;
  size_t off = 0;
  auto alloc = [&](size_t bytes) -> void* {
    void* p = ws + off; off += (bytes + 255) & ~(size_t)255; return p;
  };
  u16* qbf  = (u16*)alloc((size_t)BB*SS*DD*2);
  u16* kbf  = (u16*)alloc((size_t)BB*TT*DD*2);
  u16* vT   = (u16*)alloc((size_t)BB*DD*TT*2);
  u16* Xbf  = (u16*)alloc((size_t)BB*SS*DD*2);
  u16* Wqbf = (u16*)alloc((size_t)DD*DD*2);
  float* sq  = (float*)alloc(DD*4);
  float* sk  = (float*)alloc(DD*4);
  float* sv  = (float*)alloc(DD*4);
  float* svs = (float*)alloc(DD*4);
  u16* Sbuf = (u16*)alloc((size_t)BB*SS*TT*2);   // 64 MiB bf16 scores/probs

  prep_small<<<4, 256, 0, stream>>>(qs, ks, vs, sq, sk, svs);
  prep_sv<<<DD, 256, 0, stream>>>(Wov, bov, svs, sv);
  f32_to_bf16_k<<<4096, 256, 0, stream>>>(X, Xbf, BB*SS*DD);
  f32_to_bf16_k<<<1024, 256, 0, stream>>>(Wq, Wqbf, DD*DD);
  scale_k_k<<<4096, 256, 0, stream>>>(Y, sk, kbf, BB*TT*DD);
  dim3 tg(TT/64, DD/64, BB);
  scale_transpose_v<<<tg, 256, 0, stream>>>(Y, sv, vT);

  // Q = LN(X @ Wq.T + bq) * sigmoid(qs) / 32, bf16
  dim3 gq(DD/128, (BB*SS)/128, 1);
  gemm_bt<2><<<gq, 256, 0, stream>>>(Xbf, Wqbf, qbf, bq,
      DD, DD, DD, DD, 0, 0, 0, DD/128, (BB*SS)/128);
  ln_q<<<BB*SS, 256, 0, stream>>>(qbf, g1, b1, sq);

  // S = q @ k^T (bf16 out), all batches
  dim3 g1d(TT/128, SS/128, BB);
  gemm_bt<1><<<g1d, 256, 0, stream>>>(
      qbf, kbf, Sbuf, nullptr,
      DD, DD, DD, TT,
      (size_t)SS*DD, (size_t)TT*DD, (size_t)SS*TT, TT/128, SS/128);

  dim3 gs(SS, BB);
  softmax_rows<<<gs, 256, 0, stream>>>(Sbuf, mask);

  // out = P @ vT^T (f32 out), all batches
  dim3 g3(DD/128, SS/128, BB);
  gemm_bt<0><<<g3, 256, 0, stream>>>(
      Sbuf, vT, out, nullptr,
      TT, TT, TT, DD,
      (size_t)SS*TT, (size_t)DD*TT, (size_t)SS*DD, DD/128, SS/128);

  final_ln<<<BB*SS, 256, 0, stream>>>(X, out, g2, b2);
}